// Round 4
// baseline (5206.232 us; speedup 1.0000x reference)
//
#include <hip/hip_runtime.h>
#include <stdint.h>

// 3-layer LSTM (H=256, B=256, T=512), persistent pipelined kernel. R4.
// Partition: per layer, GB=8 batch-groups (32 rows) x GH=8 hidden-groups (32 units)
//   -> 192 workgroups of 512 threads (8 waves), ~1 WG/CU.
// R4 vs R3/R2:
//  * REVERTED LDS A-staging (R3: 6x bank conflicts, net regression). A-frags
//    load directly from the MALL-coherent ring as in R2.
//  * ONE flag per WG (not per wave): h-stores drained per-wave (s_waitcnt 0)
//    + barrier, then tid0 stores flag. Consumers poll 8 slots per array with
//    one 4B load per lane per iteration (lanes 0-7 own, 8-15 upstream).
//  * downstream-backpressure poll moved off the loop front (only guards the
//    ring h-store, checked just before it).
//  * output head stays off the critical path (after flag store).

#define Hd 256
#define Bd 256
#define Td 512
#define RING 4
#define GH 8
#define GB 8
#define CPAD 64   // uints between (l,g) flag groups (256 B)

typedef __attribute__((ext_vector_type(8))) short short8;
typedef __attribute__((ext_vector_type(4))) float floatx4;

__device__ __forceinline__ unsigned short f2bf(float f) {
  union { float f; unsigned int u; } v; v.f = f;
  return (unsigned short)((v.u + 0x7fffu + ((v.u >> 16) & 1u)) >> 16);
}
__device__ __forceinline__ float sigm(float x) { return 1.0f / (1.0f + __expf(-x)); }
__device__ __forceinline__ float tanhfast(float x) { return 2.0f / (1.0f + __expf(-2.0f * x)) - 1.0f; }

__device__ __forceinline__ unsigned int ld4(const unsigned int* p) {
  return __hip_atomic_load(p, __ATOMIC_RELAXED, __HIP_MEMORY_SCOPE_AGENT);
}
__device__ __forceinline__ unsigned long long ld8(const void* p) {
  return __hip_atomic_load((const unsigned long long*)p, __ATOMIC_RELAXED,
                           __HIP_MEMORY_SCOPE_AGENT);
}

__global__ __launch_bounds__(512, 2) void lstm3_kernel(
    const float* __restrict__ xin,
    const float* __restrict__ Wi1, const float* __restrict__ Wh1,
    const float* __restrict__ bi1, const float* __restrict__ bh1,
    const float* __restrict__ Wi2, const float* __restrict__ Wh2,
    const float* __restrict__ bi2, const float* __restrict__ bh2,
    const float* __restrict__ Wi3, const float* __restrict__ Wh3,
    const float* __restrict__ bi3, const float* __restrict__ bh3,
    const float* __restrict__ Wlin, const float* __restrict__ blin,
    float* __restrict__ out,                // [B][T], pre-zeroed
    unsigned int* __restrict__ flags,       // [3][GB][CPAD], pre-zeroed; slots 0..7 = j
    unsigned short* __restrict__ ring)      // [3][RING][B][H] bf16
{
  __shared__ float gl[4][32][33];   // [gate][local row][local unit(+pad)]

  const int bid = blockIdx.x;
  const int j   = bid / 24;         // hidden group 0..7
  const int rem = bid - j * 24;
  const int l   = rem >> 3;         // layer 0..2
  const int g   = rem & 7;          // batch group 0..7 (bid%8 -> same XCD, perf only)

  const int tid  = threadIdx.x;
  const int lane = tid & 63;
  const int wave = tid >> 6;
  const int tau  = wave & 3;        // gate: 0=i 1=f 2=g 3=o
  const int mh   = wave >> 2;       // batch half
  const int quad = lane >> 4;
  const int l15  = lane & 15;

  const int ubase = j * 32;
  const int rbase = g * 32;

  const float* Wpi = (l == 1) ? Wi2 : Wi3;
  const float* Wph = (l == 0) ? Wh1 : ((l == 1) ? Wh2 : Wh3);
  const float* bi  = (l == 0) ? bi1 : ((l == 1) ? bi2 : bi3);
  const float* bh  = (l == 0) ? bh1 : ((l == 1) ? bh2 : bh3);

  // ---- one-time: weight slice -> bf16 B-fragments in registers ----
  short8 breg[2][16];
  {
    const int koff = quad * 8;
    #pragma unroll
    for (int nt = 0; nt < 2; ++nt) {
      const int grow = tau * Hd + ubase + nt * 16 + l15;
      #pragma unroll
      for (int kc = 0; kc < 16; ++kc) {
        short8 v = {0, 0, 0, 0, 0, 0, 0, 0};
        const float* src = nullptr;
        if (kc < 8) { if (l != 0) src = Wpi + (size_t)grow * Hd + kc * 32 + koff; }
        else        { src = Wph + (size_t)grow * Hd + (kc - 8) * 32 + koff; }
        if (src) {
          #pragma unroll
          for (int e = 0; e < 8; ++e) v[e] = (short)f2bf(src[e]);
        }
        breg[nt][kc] = v;
      }
    }
  }

  // ---- combine-phase per-thread constants ----
  const int clrow = tid >> 4;
  const int cu0   = (tid & 15) * 2;
  float bsum[4][2], wiv[4][2], wlv[2];
  #pragma unroll
  for (int tt = 0; tt < 4; ++tt) {
    #pragma unroll
    for (int du = 0; du < 2; ++du) {
      const int gg = tt * Hd + ubase + cu0 + du;
      bsum[tt][du] = bi[gg] + bh[gg];
      wiv[tt][du]  = (l == 0) ? Wi1[gg] : 0.0f;
    }
  }
  wlv[0] = (l == 2) ? Wlin[ubase + cu0]     : 0.0f;
  wlv[1] = (l == 2) ? Wlin[ubase + cu0 + 1] : 0.0f;
  const float bl0 = (l == 2 && j == 0) ? blin[0] : 0.0f;

  float cst0 = 0.0f, cst1 = 0.0f;

  unsigned int* ownF = flags + (l * GB + g) * CPAD;
  unsigned int* upF  = flags + ((l - 1) * GB + g) * CPAD;   // deref only if l>0
  unsigned int* dnF  = flags + ((l + 1) * GB + g) * CPAD;   // deref only if l<2

  unsigned short* ownR = ring + (size_t)l * RING * Bd * Hd;
  const unsigned short* upRb = ring + (size_t)(l - 1) * RING * Bd * Hd;

  const int arow = rbase + mh * 16 + l15;
  const int ko   = quad * 8;
  const float* xrow = xin + (size_t)(rbase + clrow) * Td;

  const bool pollA = (lane < 8);                 // own-layer partners
  const bool pollB = (lane >= 8 && lane < 16 && l > 0);   // upstream
  const unsigned int* pA = ownF + (lane & 7);
  const unsigned int* pB = upF  + (lane & 7);

  for (int t = 0; t < Td; ++t) {
    // ---- front poll: own partners finished t-1; upstream finished t ----
    {
      const unsigned own_need = (unsigned)t;
      const unsigned up_need  = (unsigned)(t + 1);
      bool c = true;
      if (pollA) c = ld4(pA) >= own_need;
      else if (pollB) c = ld4(pB) >= up_need;
      while (!__all(c)) {
        __builtin_amdgcn_s_sleep(1);
        c = true;
        if (pollA) c = ld4(pA) >= own_need;
        else if (pollB) c = ld4(pB) >= up_need;
      }
    }

    // ---- A-fragments direct from MALL-coherent ring ----
    short8 av[16];
    if (l != 0) {
      const unsigned short* upS = upRb + (size_t)(t & (RING - 1)) * Bd * Hd
                                + (size_t)arow * Hd + ko;
      #pragma unroll
      for (int kc = 0; kc < 8; ++kc) {
        union { unsigned long long q[2]; short8 v; } u;
        u.q[0] = ld8(upS + kc * 32);
        u.q[1] = ld8(upS + kc * 32 + 4);
        av[kc] = u.v;
      }
    }
    if (t != 0) {
      const unsigned short* ownS = ownR + (size_t)((t + RING - 1) & (RING - 1)) * Bd * Hd
                                 + (size_t)arow * Hd + ko;
      #pragma unroll
      for (int kc = 0; kc < 8; ++kc) {
        union { unsigned long long q[2]; short8 v; } u;
        u.q[0] = ld8(ownS + kc * 32);
        u.q[1] = ld8(ownS + kc * 32 + 4);
        av[8 + kc] = u.v;
      }
    }

    // ---- MFMA: gates[32 rows][32 units] for gate-type tau ----
    floatx4 acc0 = {0.f, 0.f, 0.f, 0.f};
    floatx4 acc1 = {0.f, 0.f, 0.f, 0.f};
    if (l != 0) {
      #pragma unroll
      for (int kc = 0; kc < 8; ++kc) {
        acc0 = __builtin_amdgcn_mfma_f32_16x16x32_bf16(av[kc], breg[0][kc], acc0, 0, 0, 0);
        acc1 = __builtin_amdgcn_mfma_f32_16x16x32_bf16(av[kc], breg[1][kc], acc1, 0, 0, 0);
      }
    }
    if (t != 0) {
      #pragma unroll
      for (int kc = 8; kc < 16; ++kc) {
        acc0 = __builtin_amdgcn_mfma_f32_16x16x32_bf16(av[kc], breg[0][kc], acc0, 0, 0, 0);
        acc1 = __builtin_amdgcn_mfma_f32_16x16x32_bf16(av[kc], breg[1][kc], acc1, 0, 0, 0);
      }
    }

    // C layout: col(unit) = lane&15, row = quad*4 + reg
    {
      const int lr = mh * 16 + quad * 4;
      #pragma unroll
      for (int r2 = 0; r2 < 4; ++r2) {
        gl[tau][lr + r2][l15]      = acc0[r2];
        gl[tau][lr + r2][16 + l15] = acc1[r2];
      }
    }
    __syncthreads();   // barrier1: gl complete (also protects gl reuse across t)

    // ---- combine: 1 row x 2 units per thread, fp32 LSTM cell math ----
    float h0, h1;
    {
      const float xv = (l == 0) ? xrow[t] : 0.0f;
      float pi = gl[0][clrow][cu0] + bsum[0][0] + xv * wiv[0][0];
      float pf = gl[1][clrow][cu0] + bsum[1][0] + xv * wiv[1][0];
      float pg = gl[2][clrow][cu0] + bsum[2][0] + xv * wiv[2][0];
      float po = gl[3][clrow][cu0] + bsum[3][0] + xv * wiv[3][0];
      float ii = sigm(pi), ff = sigm(pf), gv = tanhfast(pg), oo = sigm(po);
      cst0 = ff * cst0 + ii * gv;
      h0 = oo * tanhfast(cst0);
      pi = gl[0][clrow][cu0 + 1] + bsum[0][1] + xv * wiv[0][1];
      pf = gl[1][clrow][cu0 + 1] + bsum[1][1] + xv * wiv[1][1];
      pg = gl[2][clrow][cu0 + 1] + bsum[2][1] + xv * wiv[2][1];
      po = gl[3][clrow][cu0 + 1] + bsum[3][1] + xv * wiv[3][1];
      ii = sigm(pi); ff = sigm(pf); gv = tanhfast(pg); oo = sigm(po);
      cst1 = ff * cst1 + ii * gv;
      h1 = oo * tanhfast(cst1);
    }

    // ---- backpressure (rarely binding): downstream must be done with slot t%RING ----
    if (l < 2 && t >= RING) {
      const unsigned dn_need = (unsigned)(t - RING + 1);
      bool c = (lane < 8) ? (ld4(&dnF[lane]) >= dn_need) : true;
      while (!__all(c)) {
        __builtin_amdgcn_s_sleep(1);
        c = (lane < 8) ? (ld4(&dnF[lane]) >= dn_need) : true;
      }
    }

    // store h pair (agent-visible relaxed store)
    {
      unsigned short* dst = ownR + (size_t)(t & (RING - 1)) * Bd * Hd
                          + (size_t)(rbase + clrow) * Hd + ubase + cu0;
      const unsigned int packed = (unsigned int)f2bf(h0) | ((unsigned int)f2bf(h1) << 16);
      __hip_atomic_store((unsigned int*)dst, packed, __ATOMIC_RELAXED,
                         __HIP_MEMORY_SCOPE_AGENT);
    }

    // ---- drain per-wave, barrier, single WG flag ----
    __builtin_amdgcn_s_waitcnt(0);   // vmcnt(0): this wave's h-stores at coherence pt
    __syncthreads();                 // all waves drained => WG's step t fully visible
    if (tid == 0) {
      __hip_atomic_store(&ownF[j], (unsigned)(t + 1), __ATOMIC_RELAXED,
                         __HIP_MEMORY_SCOPE_AGENT);
    }

    // ---- output head (layer 3), off the critical path ----
    if (l == 2) {
      float pr = wlv[0] * h0 + wlv[1] * h1;
      pr += __shfl_xor(pr, 8);
      pr += __shfl_xor(pr, 4);
      pr += __shfl_xor(pr, 2);
      pr += __shfl_xor(pr, 1);
      if ((tid & 15) == 0) {
        atomicAdd(&out[(size_t)(rbase + clrow) * Td + t], pr + bl0);
      }
    }
  }
}

extern "C" void kernel_launch(void* const* d_in, const int* in_sizes, int n_in,
                              void* d_out, int out_size, void* d_ws, size_t ws_size,
                              hipStream_t stream) {
  const float* xin  = (const float*)d_in[0];
  const float* Wi1  = (const float*)d_in[1];
  const float* Wh1  = (const float*)d_in[2];
  const float* bi1  = (const float*)d_in[3];
  const float* bh1  = (const float*)d_in[4];
  const float* Wi2  = (const float*)d_in[5];
  const float* Wh2  = (const float*)d_in[6];
  const float* bi2  = (const float*)d_in[7];
  const float* bh2  = (const float*)d_in[8];
  const float* Wi3  = (const float*)d_in[9];
  const float* Wh3  = (const float*)d_in[10];
  const float* bi3  = (const float*)d_in[11];
  const float* bh3  = (const float*)d_in[12];
  const float* Wlin = (const float*)d_in[13];
  const float* blin = (const float*)d_in[14];
  float* out = (float*)d_out;

  unsigned int*   flags = (unsigned int*)d_ws;
  unsigned short* ring  = (unsigned short*)((char*)d_ws + 8192);
  // ws usage: 8192 B flags (3*8*64*4 = 6144 used) + 3*RING*B*H*2 B rings (~1.5 MB)

  hipMemsetAsync(d_ws, 0, 8192, stream);
  hipMemsetAsync(d_out, 0, (size_t)out_size * sizeof(float), stream);

  lstm3_kernel<<<dim3(3 * GB * GH), dim3(512), 0, stream>>>(
      xin, Wi1, Wh1, bi1, bh1, Wi2, Wh2, bi2, bh2,
      Wi3, Wh3, bi3, bh3, Wlin, blin, out, flags, ring);
}

// Round 7
// 4631.105 us; speedup vs baseline: 1.1242x; 1.1242x over previous
//
#include <hip/hip_runtime.h>
#include <stdint.h>

// 3-layer LSTM (H=256, B=256, T=512), persistent pipelined kernel. R7.
// Base = R2 (session-best 4.59 ms), intrinsics only (R5/R6 sc0-asm bricked).
// R7 vs R2 (two minimal changes, everything else byte-identical):
//  1. poll loop is a SINGLE non-divergent loop: lanes 0/1/2 each own one
//     condition, combined with __all ballot. R2 ran three divergent while
//     loops (exec-mask serialized -> sum of latencies, not max).
//  2. HOT spin: no s_sleep between poll iterations (tests DVFS/detection-
//     granularity hypothesis; relaxed loads, so no cache-maintenance cost).

#define Hd 256
#define Bd 256
#define Td 512
#define RING 4
#define GH 8
#define GB 8
#define CPAD 32   // 32 uints = 128 B between flag counters

typedef __attribute__((ext_vector_type(8))) short short8;
typedef __attribute__((ext_vector_type(4))) float floatx4;

__device__ __forceinline__ unsigned short f2bf(float f) {
  union { float f; unsigned int u; } v; v.f = f;
  return (unsigned short)((v.u + 0x7fffu + ((v.u >> 16) & 1u)) >> 16);
}
__device__ __forceinline__ float sigm(float x) { return 1.0f / (1.0f + __expf(-x)); }
__device__ __forceinline__ float tanhfast(float x) { return 2.0f / (1.0f + __expf(-2.0f * x)) - 1.0f; }

__device__ __forceinline__ unsigned ld4(const unsigned* p) {
  return __hip_atomic_load(p, __ATOMIC_RELAXED, __HIP_MEMORY_SCOPE_AGENT);
}
__device__ __forceinline__ unsigned long long ld8(const void* p) {
  return __hip_atomic_load((const unsigned long long*)p, __ATOMIC_RELAXED,
                           __HIP_MEMORY_SCOPE_AGENT);
}

__global__ __launch_bounds__(512, 2) void lstm3_kernel(
    const float* __restrict__ xin,
    const float* __restrict__ Wi1, const float* __restrict__ Wh1,
    const float* __restrict__ bi1, const float* __restrict__ bh1,
    const float* __restrict__ Wi2, const float* __restrict__ Wh2,
    const float* __restrict__ bi2, const float* __restrict__ bh2,
    const float* __restrict__ Wi3, const float* __restrict__ Wh3,
    const float* __restrict__ bi3, const float* __restrict__ bh3,
    const float* __restrict__ Wlin, const float* __restrict__ blin,
    float* __restrict__ out,                // [B][T], pre-zeroed
    unsigned int* __restrict__ cnt,         // [3*GB*CPAD], pre-zeroed
    unsigned short* __restrict__ ring)      // [3][RING][B][H] bf16
{
  __shared__ float gl[4][32][33];   // [gate][local row][local unit(+pad)]

  const int bid = blockIdx.x;
  const int j   = bid / 24;         // hidden group 0..7
  const int rem = bid - j * 24;
  const int l   = rem >> 3;         // layer 0..2
  const int g   = rem & 7;          // batch group 0..7 (bid%8 -> same XCD, perf only)

  const int tid  = threadIdx.x;
  const int lane = tid & 63;
  const int wave = tid >> 6;
  const int tau  = wave & 3;        // gate: 0=i 1=f 2=g 3=o
  const int mh   = wave >> 2;       // batch half
  const int quad = lane >> 4;
  const int l15  = lane & 15;

  const int ubase = j * 32;
  const int rbase = g * 32;

  const float* Wpi = (l == 1) ? Wi2 : Wi3;
  const float* Wph = (l == 0) ? Wh1 : ((l == 1) ? Wh2 : Wh3);
  const float* bi  = (l == 0) ? bi1 : ((l == 1) ? bi2 : bi3);
  const float* bh  = (l == 0) ? bh1 : ((l == 1) ? bh2 : bh3);

  // ---- one-time: weight slice -> bf16 B-fragments in registers ----
  short8 breg[2][16];
  {
    const int koff = quad * 8;
    #pragma unroll
    for (int nt = 0; nt < 2; ++nt) {
      const int grow = tau * Hd + ubase + nt * 16 + l15;
      #pragma unroll
      for (int kc = 0; kc < 16; ++kc) {
        short8 v = {0, 0, 0, 0, 0, 0, 0, 0};
        const float* src = nullptr;
        if (kc < 8) { if (l != 0) src = Wpi + (size_t)grow * Hd + kc * 32 + koff; }
        else        { src = Wph + (size_t)grow * Hd + (kc - 8) * 32 + koff; }
        if (src) {
          #pragma unroll
          for (int e = 0; e < 8; ++e) v[e] = (short)f2bf(src[e]);
        }
        breg[nt][kc] = v;
      }
    }
  }

  // ---- combine-phase per-thread constants ----
  const int clrow = tid >> 4;
  const int cu0   = (tid & 15) * 2;
  float bsum[4][2], wiv[4][2], wlv[2];
  #pragma unroll
  for (int tt = 0; tt < 4; ++tt) {
    #pragma unroll
    for (int du = 0; du < 2; ++du) {
      const int gg = tt * Hd + ubase + cu0 + du;
      bsum[tt][du] = bi[gg] + bh[gg];
      wiv[tt][du]  = (l == 0) ? Wi1[gg] : 0.0f;
    }
  }
  wlv[0] = (l == 2) ? Wlin[ubase + cu0]     : 0.0f;
  wlv[1] = (l == 2) ? Wlin[ubase + cu0 + 1] : 0.0f;
  const float bl0 = (l == 2 && j == 0) ? blin[0] : 0.0f;

  float cst0 = 0.0f, cst1 = 0.0f;

  unsigned int* myC = cnt + (l * GB + g) * CPAD;
  unsigned int* upC = cnt + ((l - 1) * GB + g) * CPAD;   // deref only if l>0
  unsigned int* dnC = cnt + ((l + 1) * GB + g) * CPAD;   // deref only if l<2
  unsigned short* ownR = ring + (size_t)l * RING * Bd * Hd;
  const unsigned short* upRb = ring + (size_t)(l - 1) * RING * Bd * Hd;

  const int arow = rbase + mh * 16 + l15;
  const int ko   = quad * 8;
  const float* xrow = xin + (size_t)(rbase + clrow) * Td;

  // poll roles: wave-0 lanes 0/1/2 own the three conditions (non-divergent)
  const bool r0 = (tid == 0);
  const bool r1 = (tid == 1) && (l > 0);
  const bool r2 = (tid == 2) && (l < 2);
  const unsigned int* pp = r0 ? myC : (r1 ? upC : (r2 ? dnC : myC));

  for (int t = 0; t < Td; ++t) {
    // ---- single non-divergent hot poll (all three conditions in one loop) ----
    {
      const bool act = (r0 && t > 0) || r1 || (r2 && t >= RING);
      const unsigned need = r0 ? (unsigned)(GH * t)
                          : r1 ? (unsigned)(GH * (t + 1))
                               : (unsigned)(GH * (t - RING + 1));
      bool c = !act || (ld4(pp) >= need);
      while (!__all(c)) {
        c = !act || (ld4(pp) >= need);
      }
    }
    __syncthreads();

    // ---- prefetch all A-fragments (MALL-coherent relaxed loads) ----
    short8 av[16];
    if (l != 0) {
      const unsigned short* upS = upRb + (size_t)(t & (RING - 1)) * Bd * Hd
                                + (size_t)arow * Hd + ko;
      #pragma unroll
      for (int kc = 0; kc < 8; ++kc) {
        union { unsigned long long q[2]; short8 v; } u;
        u.q[0] = ld8(upS + kc * 32);
        u.q[1] = ld8(upS + kc * 32 + 4);
        av[kc] = u.v;
      }
    }
    if (t != 0) {
      const unsigned short* ownS = ownR + (size_t)((t + RING - 1) & (RING - 1)) * Bd * Hd
                                 + (size_t)arow * Hd + ko;
      #pragma unroll
      for (int kc = 0; kc < 8; ++kc) {
        union { unsigned long long q[2]; short8 v; } u;
        u.q[0] = ld8(ownS + kc * 32);
        u.q[1] = ld8(ownS + kc * 32 + 4);
        av[8 + kc] = u.v;
      }
    }

    // ---- MFMA: gates[32 rows][32 units] for gate-type tau ----
    floatx4 acc0 = {0.f, 0.f, 0.f, 0.f};
    floatx4 acc1 = {0.f, 0.f, 0.f, 0.f};
    if (l != 0) {
      #pragma unroll
      for (int kc = 0; kc < 8; ++kc) {
        acc0 = __builtin_amdgcn_mfma_f32_16x16x32_bf16(av[kc], breg[0][kc], acc0, 0, 0, 0);
        acc1 = __builtin_amdgcn_mfma_f32_16x16x32_bf16(av[kc], breg[1][kc], acc1, 0, 0, 0);
      }
    }
    if (t != 0) {
      #pragma unroll
      for (int kc = 8; kc < 16; ++kc) {
        acc0 = __builtin_amdgcn_mfma_f32_16x16x32_bf16(av[kc], breg[0][kc], acc0, 0, 0, 0);
        acc1 = __builtin_amdgcn_mfma_f32_16x16x32_bf16(av[kc], breg[1][kc], acc1, 0, 0, 0);
      }
    }

    // C layout: col(unit) = lane&15, row = quad*4 + reg
    {
      const int lr = mh * 16 + quad * 4;
      #pragma unroll
      for (int r2i = 0; r2i < 4; ++r2i) {
        gl[tau][lr + r2i][l15]      = acc0[r2i];
        gl[tau][lr + r2i][16 + l15] = acc1[r2i];
      }
    }
    __syncthreads();

    // ---- combine: 1 row x 2 units per thread, fp32 LSTM cell math ----
    float h0, h1;
    {
      const float xv = (l == 0) ? xrow[t] : 0.0f;
      float pi = gl[0][clrow][cu0] + bsum[0][0] + xv * wiv[0][0];
      float pf = gl[1][clrow][cu0] + bsum[1][0] + xv * wiv[1][0];
      float pg = gl[2][clrow][cu0] + bsum[2][0] + xv * wiv[2][0];
      float po = gl[3][clrow][cu0] + bsum[3][0] + xv * wiv[3][0];
      float ii = sigm(pi), ff = sigm(pf), gv = tanhfast(pg), oo = sigm(po);
      cst0 = ff * cst0 + ii * gv;
      h0 = oo * tanhfast(cst0);
      pi = gl[0][clrow][cu0 + 1] + bsum[0][1] + xv * wiv[0][1];
      pf = gl[1][clrow][cu0 + 1] + bsum[1][1] + xv * wiv[1][1];
      pg = gl[2][clrow][cu0 + 1] + bsum[2][1] + xv * wiv[2][1];
      po = gl[3][clrow][cu0 + 1] + bsum[3][1] + xv * wiv[3][1];
      ii = sigm(pi); ff = sigm(pf); gv = tanhfast(pg); oo = sigm(po);
      cst1 = ff * cst1 + ii * gv;
      h1 = oo * tanhfast(cst1);
    }

    // store h pair (MALL write-through, relaxed)
    {
      unsigned short* dst = ownR + (size_t)(t & (RING - 1)) * Bd * Hd
                          + (size_t)(rbase + clrow) * Hd + ubase + cu0;
      const unsigned int packed = (unsigned int)f2bf(h0) | ((unsigned int)f2bf(h1) << 16);
      __hip_atomic_store((unsigned int*)dst, packed, __ATOMIC_RELAXED,
                         __HIP_MEMORY_SCOPE_AGENT);
    }

    // ---- output head folded into layer 3 ----
    if (l == 2) {
      float pr = wlv[0] * h0 + wlv[1] * h1;
      pr += __shfl_xor(pr, 8);
      pr += __shfl_xor(pr, 4);
      pr += __shfl_xor(pr, 2);
      pr += __shfl_xor(pr, 1);
      if ((tid & 15) == 0) {
        atomicAdd(&out[(size_t)(rbase + clrow) * Td + t], pr + bl0);
      }
    }

    __syncthreads();   // barrier drains vmcnt: all h-stores visible before flag
    if (tid == 0) {
      __hip_atomic_fetch_add(myC, 1u, __ATOMIC_RELAXED, __HIP_MEMORY_SCOPE_AGENT);
    }
  }
}

extern "C" void kernel_launch(void* const* d_in, const int* in_sizes, int n_in,
                              void* d_out, int out_size, void* d_ws, size_t ws_size,
                              hipStream_t stream) {
  const float* xin  = (const float*)d_in[0];
  const float* Wi1  = (const float*)d_in[1];
  const float* Wh1  = (const float*)d_in[2];
  const float* bi1  = (const float*)d_in[3];
  const float* bh1  = (const float*)d_in[4];
  const float* Wi2  = (const float*)d_in[5];
  const float* Wh2  = (const float*)d_in[6];
  const float* bi2  = (const float*)d_in[7];
  const float* bh2  = (const float*)d_in[8];
  const float* Wi3  = (const float*)d_in[9];
  const float* Wh3  = (const float*)d_in[10];
  const float* bi3  = (const float*)d_in[11];
  const float* bh3  = (const float*)d_in[12];
  const float* Wlin = (const float*)d_in[13];
  const float* blin = (const float*)d_in[14];
  float* out = (float*)d_out;

  unsigned int*   cnt  = (unsigned int*)d_ws;
  unsigned short* ring = (unsigned short*)((char*)d_ws + 4096);
  // ws usage: 4096 B padded counters + 3*RING*B*H*2 B rings (~1.5 MB)

  hipMemsetAsync(d_ws, 0, 4096, stream);
  hipMemsetAsync(d_out, 0, (size_t)out_size * sizeof(float), stream);

  lstm3_kernel<<<dim3(3 * GB * GH), dim3(512), 0, stream>>>(
      xin, Wi1, Wh1, bi1, bh1, Wi2, Wh2, bi2, bh2,
      Wi3, Wh3, bi3, bh3, Wlin, blin, out, cnt, ring);
}